// Round 12
// baseline (67.673 us; speedup 1.0000x reference)
//
#include <hip/hip_runtime.h>

#define GN 192
#define GNN (GN * GN)
#define GTOT (GN * GN * GN)   // 7,077,888 = 27,648 * 256
#define NSLOTS 256

// acc layout in d_ws: double acc[NSLOTS][2]  (mom, cont) = 4 KB

// ---- raw buffer-load intrinsics (CK-style): compiler-tracked wide loads ----
typedef int   int32x4_t  __attribute__((ext_vector_type(4)));
typedef float floatx4_t  __attribute__((ext_vector_type(4)));

extern "C" __device__ floatx4_t
llvm_amdgcn_raw_buffer_load_fp32x4(int32x4_t srsrc, int voffset, int soffset,
                                   int aux) __asm("llvm.amdgcn.raw.buffer.load.v4f32");
extern "C" __device__ float
llvm_amdgcn_raw_buffer_load_fp32(int32x4_t srsrc, int voffset, int soffset,
                                 int aux) __asm("llvm.amdgcn.raw.buffer.load.f32");

// SRD: base | stride=0, num_records = exact bytes (OOB dwords read 0 -> the
// 4B tail overread of each dwordx4 at the array end is hardware-safe),
// word3 = 0x00020000 (raw untyped dword).
__device__ __forceinline__ int32x4_t make_srd(const void* ptr, unsigned bytes) {
    int32x4_t r;
    unsigned long long a = (unsigned long long)ptr;
    r.x = (int)(unsigned)(a & 0xFFFFFFFFu);
    r.y = (int)(unsigned)(a >> 32);
    r.z = (int)bytes;
    r.w = 0x00020000;
    return r;
}

// __launch_bounds__(256, 4): min 4 waves/EU -> VGPR budget 128. The default
// (occupancy-max) allocation was 28 VGPR, which forcibly serializes the 15
// buffer loads (results can't coexist). 128-reg budget lets all 15 issue
// back-to-back with one waitcnt group -> one L2-latency exposure, not ~6.
__global__ __launch_bounds__(256, 4) void ns_loss_kernel(
    const float* __restrict__ u,      // (N,N,N,3)
    const float* __restrict__ uprev,  // (N,N,N,3)
    const float* __restrict__ p,      // (N,N,N)
    const float* __restrict__ rho,    // (N,N,N)
    const float* __restrict__ nu,     // (1,)
    const float* __restrict__ h,      // (3,)
    const float* __restrict__ dt,     // (1,)
    const float* __restrict__ grav,   // (3,)
    double* __restrict__ acc)
{
    const int idx = blockIdx.x * 256 + threadIdx.x;   // < GTOT exactly
    const int k = idx % GN;
    const int t = idx / GN;
    const int j = t % GN;
    const int i = t / GN;

    // periodic neighbor cell indices
    const int kp = (k == GN - 1) ? idx - (GN - 1)       : idx + 1;
    const int km = (k == 0)      ? idx + (GN - 1)       : idx - 1;
    const int jp = (j == GN - 1) ? idx - (GN - 1) * GN  : idx + GN;
    const int jm = (j == 0)      ? idx + (GN - 1) * GN  : idx - GN;
    const int ip = (i == GN - 1) ? idx - (GN - 1) * GNN : idx + GNN;
    const int im = (i == 0)      ? idx + (GN - 1) * GNN : idx - GNN;

    const int32x4_t srd_u  = make_srd(u,     (unsigned)GTOT * 12u);
    const int32x4_t srd_up = make_srd(uprev, (unsigned)GTOT * 12u);
    const int32x4_t srd_p  = make_srd(p,     (unsigned)GTOT * 4u);
    const int32x4_t srd_r  = make_srd(rho,   (unsigned)GTOT * 4u);

    // ---- gathers: 7 u-vectors + uprev as dwordx4, p/rho as dwords ----
    const floatx4_t vc  = llvm_amdgcn_raw_buffer_load_fp32x4(srd_u, 12 * idx, 0, 0);
    const floatx4_t vxp = llvm_amdgcn_raw_buffer_load_fp32x4(srd_u, 12 * ip,  0, 0);
    const floatx4_t vxm = llvm_amdgcn_raw_buffer_load_fp32x4(srd_u, 12 * im,  0, 0);
    const floatx4_t vyp = llvm_amdgcn_raw_buffer_load_fp32x4(srd_u, 12 * jp,  0, 0);
    const floatx4_t vym = llvm_amdgcn_raw_buffer_load_fp32x4(srd_u, 12 * jm,  0, 0);
    const floatx4_t vzp = llvm_amdgcn_raw_buffer_load_fp32x4(srd_u, 12 * kp,  0, 0);
    const floatx4_t vzm = llvm_amdgcn_raw_buffer_load_fp32x4(srd_u, 12 * km,  0, 0);
    const floatx4_t vup = llvm_amdgcn_raw_buffer_load_fp32x4(srd_up, 12 * idx, 0, 0);
    const float pxp = llvm_amdgcn_raw_buffer_load_fp32(srd_p, 4 * ip, 0, 0);
    const float pxm = llvm_amdgcn_raw_buffer_load_fp32(srd_p, 4 * im, 0, 0);
    const float pyp = llvm_amdgcn_raw_buffer_load_fp32(srd_p, 4 * jp, 0, 0);
    const float pym = llvm_amdgcn_raw_buffer_load_fp32(srd_p, 4 * jm, 0, 0);
    const float pzp = llvm_amdgcn_raw_buffer_load_fp32(srd_p, 4 * kp, 0, 0);
    const float pzm = llvm_amdgcn_raw_buffer_load_fp32(srd_p, 4 * km, 0, 0);
    const float rr  = llvm_amdgcn_raw_buffer_load_fp32(srd_r, 4 * idx, 0, 0);

    // uniform scalars
    const float h0 = h[0], h1 = h[1], h2 = h[2];
    const float i2h0 = 0.5f / h0, i2h1 = 0.5f / h1, i2h2 = 0.5f / h2;
    const float ihs0 = 1.0f / (h0 * h0), ihs1 = 1.0f / (h1 * h1), ihs2 = 1.0f / (h2 * h2);
    const float invdt = 1.0f / dt[0];
    const float nu0 = nu[0];
    const float g0 = grav[0], g1 = grav[1], g2 = grav[2];

    const float ucx = vc.x,  ucy = vc.y,  ucz = vc.z;
    const float xpx = vxp.x, xpy = vxp.y, xpz = vxp.z;
    const float xmx = vxm.x, xmy = vxm.y, xmz = vxm.z;
    const float ypx = vyp.x, ypy = vyp.y, ypz = vyp.z;
    const float ymx = vym.x, ymy = vym.y, ymz = vym.z;
    const float zpx = vzp.x, zpy = vzp.y, zpz = vzp.z;
    const float zmx = vzm.x, zmy = vzm.y, zmz = vzm.z;

    // central differences
    const float dXx = (xpx - xmx) * i2h0, dXy = (xpy - xmy) * i2h0, dXz = (xpz - xmz) * i2h0;
    const float dYx = (ypx - ymx) * i2h1, dYy = (ypy - ymy) * i2h1, dYz = (ypz - ymz) * i2h1;
    const float dZx = (zpx - zmx) * i2h2, dZy = (zpy - zmy) * i2h2, dZz = (zpz - zmz) * i2h2;

    // laplacians
    const float lapx = (xpx - 2.0f * ucx + xmx) * ihs0 + (ypx - 2.0f * ucx + ymx) * ihs1 + (zpx - 2.0f * ucx + zmx) * ihs2;
    const float lapy = (xpy - 2.0f * ucy + xmy) * ihs0 + (ypy - 2.0f * ucy + ymy) * ihs1 + (zpy - 2.0f * ucy + zmy) * ihs2;
    const float lapz = (xpz - 2.0f * ucz + xmz) * ihs0 + (ypz - 2.0f * ucz + ymz) * ihs1 + (zpz - 2.0f * ucz + zmz) * ihs2;

    // convection
    const float convx = ucx * dXx + ucy * dYx + ucz * dZx;
    const float convy = ucx * dXy + ucy * dYy + ucz * dZy;
    const float convz = ucx * dXz + ucy * dYz + ucz * dZz;

    // pressure gradient
    const float dpx = (pxp - pxm) * i2h0;
    const float dpy = (pyp - pym) * i2h1;
    const float dpz = (pzp - pzm) * i2h2;

    const float inv_rho = __builtin_amdgcn_rcpf(rr + 1e-8f);

    const float dudtx = (ucx - vup.x) * invdt;
    const float dudty = (ucy - vup.y) * invdt;
    const float dudtz = (ucz - vup.z) * invdt;

    const float Rx = dudtx + convx + dpx * inv_rho - nu0 * lapx - g0;
    const float Ry = dudty + convy + dpy * inv_rho - nu0 * lapy - g1;
    const float Rz = dudtz + convz + dpz * inv_rho - nu0 * lapz - g2;
    const float Rc = dXx + dYy + dZz;

    // per-thread partial in fp32; wave(64) reduce in fp32 (12 shuffles)
    float msum = Rx * Rx + Ry * Ry + Rz * Rz;
    float csum = Rc * Rc;
    #pragma unroll
    for (int off = 32; off > 0; off >>= 1) {
        msum += __shfl_down(msum, off);
        csum += __shfl_down(csum, off);
    }

    __shared__ double smom[4], scont[4];
    const int wid = threadIdx.x >> 6;
    const int lane = threadIdx.x & 63;
    if (lane == 0) { smom[wid] = (double)msum; scont[wid] = (double)csum; }
    __syncthreads();
    if (threadIdx.x == 0) {
        const double m = smom[0] + smom[1] + smom[2] + smom[3];
        const double c = scont[0] + scont[1] + scont[2] + scont[3];
        double* slot = acc + 2 * (blockIdx.x & (NSLOTS - 1));
        unsafeAtomicAdd(slot, m);
        unsafeAtomicAdd(slot + 1, c);
    }
}

__global__ __launch_bounds__(256) void ns_finalize_kernel(const double* __restrict__ acc,
                                                          float* __restrict__ out)
{
    const int tid = threadIdx.x;
    double mom = acc[2 * tid];
    double cont = acc[2 * tid + 1];
    #pragma unroll
    for (int off = 32; off > 0; off >>= 1) {
        mom  += __shfl_down(mom, off);
        cont += __shfl_down(cont, off);
    }
    __shared__ double smom[4], scont[4];
    const int wid = tid >> 6;
    const int lane = tid & 63;
    if (lane == 0) { smom[wid] = mom; scont[wid] = cont; }
    __syncthreads();
    if (tid == 0) {
        const double m = (smom[0] + smom[1] + smom[2] + smom[3]) / (double)GTOT;
        const double c = (scont[0] + scont[1] + scont[2] + scont[3]) / (double)GTOT;
        out[0] = (float)(m + 10.0 * c);
        out[1] = (float)m;
        out[2] = (float)c;
    }
}

extern "C" void kernel_launch(void* const* d_in, const int* in_sizes, int n_in,
                              void* d_out, int out_size, void* d_ws, size_t ws_size,
                              hipStream_t stream)
{
    const float* u     = (const float*)d_in[0];
    const float* uprev = (const float*)d_in[1];
    const float* p     = (const float*)d_in[2];
    const float* rho   = (const float*)d_in[3];
    const float* nu    = (const float*)d_in[4];
    const float* h     = (const float*)d_in[5];
    const float* dt    = (const float*)d_in[6];
    const float* grav  = (const float*)d_in[7];

    double* acc = (double*)d_ws;

    (void)hipMemsetAsync(d_ws, 0, NSLOTS * 2 * sizeof(double), stream);

    ns_loss_kernel<<<GTOT / 256, 256, 0, stream>>>(u, uprev, p, rho, nu, h, dt, grav, acc);
    ns_finalize_kernel<<<1, 256, 0, stream>>>(acc, (float*)d_out);
}

// Round 13
// 50.270 us; speedup vs baseline: 1.3462x; 1.3462x over previous
//
#include <hip/hip_runtime.h>

#define GN 192
#define GNN (GN * GN)
#define GTOT (GN * GN * GN)   // 7,077,888
#define NSLOTS 256
#define NT (GTOT / 2)         // 3,538,944 threads (2 cells each)
#define NBLK (NT / 256)       // 13,824 blocks
#define CHUNK (NBLK / 8)      // 1,728  (13824 % 8 == 0 -> bijective swizzle)

typedef int   int32x4_t __attribute__((ext_vector_type(4)));
typedef float floatx4_t __attribute__((ext_vector_type(4)));
typedef float floatx2_t __attribute__((ext_vector_type(2)));

extern "C" __device__ floatx4_t
llvm_amdgcn_raw_buffer_load_fp32x4(int32x4_t srsrc, int voffset, int soffset,
                                   int aux) __asm("llvm.amdgcn.raw.buffer.load.v4f32");
extern "C" __device__ floatx2_t
llvm_amdgcn_raw_buffer_load_fp32x2(int32x4_t srsrc, int voffset, int soffset,
                                   int aux) __asm("llvm.amdgcn.raw.buffer.load.v2f32");
extern "C" __device__ float
llvm_amdgcn_raw_buffer_load_fp32(int32x4_t srsrc, int voffset, int soffset,
                                 int aux) __asm("llvm.amdgcn.raw.buffer.load.f32");

__device__ __forceinline__ int32x4_t make_srd(const void* ptr, unsigned bytes) {
    int32x4_t r;
    unsigned long long a = (unsigned long long)ptr;
    r.x = (int)(unsigned)(a & 0xFFFFFFFFu);
    r.y = (int)(unsigned)(a >> 32);
    r.z = (int)bytes;          // OOB dwords read 0 (tail overreads are safe+unused)
    r.w = 0x00020000;
    return r;
}

typedef float v2 __attribute__((ext_vector_type(2)));

__global__ __launch_bounds__(256, 2) void ns_loss_kernel(
    const float* __restrict__ u,      // (N,N,N,3)
    const float* __restrict__ uprev,  // (N,N,N,3)
    const float* __restrict__ p,      // (N,N,N)
    const float* __restrict__ rho,    // (N,N,N)
    const float* __restrict__ nu,
    const float* __restrict__ h,
    const float* __restrict__ dt,
    const float* __restrict__ grav,
    double* __restrict__ acc)
{
    const int d = blockIdx.x;
    const int o = (d & 7) * CHUNK + (d >> 3);       // XCD-chunked, bijective
    const int g = o * 256 + threadIdx.x;            // pair index < NT
    const int m  = g % 96;                          // 96 pairs per k-line
    const int ln = g / 96;                          // line = i*GN + j
    const int j  = ln % GN;
    const int i  = ln / GN;
    const int k0 = 2 * m;                           // even; k1 = k0+1 <= 191
    const int c0 = ln * GN + k0;
    const int c1 = c0 + 1;

    // wrapped neighbor cell indices (shared by the pair where possible)
    const int zmc = (k0 == 0)   ? c0 + (GN - 1) : c0 - 1;     // cell (k0-1)
    const int zpc = (k0 == GN-2)? c1 - (GN - 1) : c1 + 1;     // cell (k1+1)
    const int ipb = (i == GN-1) ? c0 - (GN - 1) * GNN : c0 + GNN;
    const int imb = (i == 0)    ? c0 + (GN - 1) * GNN : c0 - GNN;
    const int jpb = (j == GN-1) ? c0 - (GN - 1) * GN  : c0 + GN;
    const int jmb = (j == 0)    ? c0 + (GN - 1) * GN  : c0 - GN;

    const int32x4_t srd_u  = make_srd(u,     (unsigned)GTOT * 12u);
    const int32x4_t srd_up = make_srd(uprev, (unsigned)GTOT * 12u);
    const int32x4_t srd_p  = make_srd(p,     (unsigned)GTOT * 4u);
    const int32x4_t srd_r  = make_srd(rho,   (unsigned)GTOT * 4u);

    // ---- 22 independent loads for the cell pair ----
    // z-line u: A=u[zm0], B=u[c0]+u[c1].x, C2=u[c1].yz+junk, D=u[zp1]
    const floatx4_t A  = llvm_amdgcn_raw_buffer_load_fp32x4(srd_u, 12 * zmc, 0, 0);
    const floatx4_t B  = llvm_amdgcn_raw_buffer_load_fp32x4(srd_u, 12 * c0, 0, 0);
    const floatx4_t C2 = llvm_amdgcn_raw_buffer_load_fp32x4(srd_u, 12 * c0 + 16, 0, 0);
    const floatx4_t D  = llvm_amdgcn_raw_buffer_load_fp32x4(srd_u, 12 * zpc, 0, 0);
    // i+1 / i-1 / j+1 / j-1 pairs: two x4 each (6 of 8 dwords used)
    const floatx4_t E1 = llvm_amdgcn_raw_buffer_load_fp32x4(srd_u, 12 * ipb, 0, 0);
    const floatx4_t E2 = llvm_amdgcn_raw_buffer_load_fp32x4(srd_u, 12 * ipb + 16, 0, 0);
    const floatx4_t G1 = llvm_amdgcn_raw_buffer_load_fp32x4(srd_u, 12 * imb, 0, 0);
    const floatx4_t G2 = llvm_amdgcn_raw_buffer_load_fp32x4(srd_u, 12 * imb + 16, 0, 0);
    const floatx4_t I1 = llvm_amdgcn_raw_buffer_load_fp32x4(srd_u, 12 * jpb, 0, 0);
    const floatx4_t I2 = llvm_amdgcn_raw_buffer_load_fp32x4(srd_u, 12 * jpb + 16, 0, 0);
    const floatx4_t K1 = llvm_amdgcn_raw_buffer_load_fp32x4(srd_u, 12 * jmb, 0, 0);
    const floatx4_t K2 = llvm_amdgcn_raw_buffer_load_fp32x4(srd_u, 12 * jmb + 16, 0, 0);
    // uprev pair
    const floatx4_t M  = llvm_amdgcn_raw_buffer_load_fp32x4(srd_up, 12 * c0, 0, 0);
    const floatx4_t M2 = llvm_amdgcn_raw_buffer_load_fp32x4(srd_up, 12 * c0 + 16, 0, 0);
    // pressure: center pair + z-halos + 4 neighbor pairs
    const floatx2_t P0  = llvm_amdgcn_raw_buffer_load_fp32x2(srd_p, 4 * c0, 0, 0);
    const float     pzm = llvm_amdgcn_raw_buffer_load_fp32(srd_p, 4 * zmc, 0, 0);
    const float     pzp = llvm_amdgcn_raw_buffer_load_fp32(srd_p, 4 * zpc, 0, 0);
    const floatx2_t Pip = llvm_amdgcn_raw_buffer_load_fp32x2(srd_p, 4 * ipb, 0, 0);
    const floatx2_t Pim = llvm_amdgcn_raw_buffer_load_fp32x2(srd_p, 4 * imb, 0, 0);
    const floatx2_t Pjp = llvm_amdgcn_raw_buffer_load_fp32x2(srd_p, 4 * jpb, 0, 0);
    const floatx2_t Pjm = llvm_amdgcn_raw_buffer_load_fp32x2(srd_p, 4 * jmb, 0, 0);
    // rho pair
    const floatx2_t RR  = llvm_amdgcn_raw_buffer_load_fp32x2(srd_r, 4 * c0, 0, 0);

    // uniform scalars
    const float h0 = h[0], h1v = h[1], h2v = h[2];
    const float i2h0 = 0.5f / h0, i2h1 = 0.5f / h1v, i2h2 = 0.5f / h2v;
    const float ihs0 = 1.0f / (h0 * h0), ihs1 = 1.0f / (h1v * h1v), ihs2 = 1.0f / (h2v * h2v);
    const float invdt = 1.0f / dt[0];
    const float nu0 = nu[0];
    const float g0 = grav[0], g1v = grav[1], g2v = grav[2];
    const float s2h = 2.0f * (ihs0 + ihs1 + ihs2);

    // Pin: no load may sink below this point -> all 22 stay outstanding
    // (vmcnt bookkeeping remains compiler-managed and correct).
    __builtin_amdgcn_sched_barrier(0);

    // ---- pack cell pair into v2 lanes (.x = cell0, .y = cell1) ----
    const v2 ucx = {B.x, B.w},  ucy = {B.y, C2.x}, ucz = {B.z, C2.y};
    const v2 zmx = {A.x, B.x},  zmy = {A.y, B.y},  zmz = {A.z, B.z};
    const v2 zpx = {B.w, D.x},  zpy = {C2.x, D.y}, zpz = {C2.y, D.z};
    const v2 xpx = {E1.x, E1.w}, xpy = {E1.y, E2.x}, xpz = {E1.z, E2.y};
    const v2 xmx = {G1.x, G1.w}, xmy = {G1.y, G2.x}, xmz = {G1.z, G2.y};
    const v2 ypx = {I1.x, I1.w}, ypy = {I1.y, I2.x}, ypz = {I1.z, I2.y};
    const v2 ymx = {K1.x, K1.w}, ymy = {K1.y, K2.x}, ymz = {K1.z, K2.y};
    const v2 upx = {M.x, M.w},  upy = {M.y, M2.x}, upz = {M.z, M2.y};
    const v2 pzm2 = {pzm, P0.x}, pzp2 = {P0.y, pzp};

    // ---- packed stencil math (validated form from round 6) ----
    v2 dXx = (xpx - xmx) * i2h0, dXy = (xpy - xmy) * i2h0, dXz = (xpz - xmz) * i2h0;
    v2 dYx = (ypx - ymx) * i2h1, dYy = (ypy - ymy) * i2h1, dYz = (ypz - ymz) * i2h1;
    v2 dZx = (zpx - zmx) * i2h2, dZy = (zpy - zmy) * i2h2, dZz = (zpz - zmz) * i2h2;

    v2 lapx = (xpx + xmx) * ihs0 + (ypx + ymx) * ihs1 + (zpx + zmx) * ihs2 - ucx * s2h;
    v2 lapy = (xpy + xmy) * ihs0 + (ypy + ymy) * ihs1 + (zpy + zmy) * ihs2 - ucy * s2h;
    v2 lapz = (xpz + xmz) * ihs0 + (ypz + ymz) * ihs1 + (zpz + zmz) * ihs2 - ucz * s2h;

    v2 convx = ucx * dXx + ucy * dYx + ucz * dZx;
    v2 convy = ucx * dXy + ucy * dYy + ucz * dZy;
    v2 convz = ucx * dXz + ucy * dYz + ucz * dZz;

    v2 dpx = (Pip - Pim) * i2h0;
    v2 dpy = (Pjp - Pjm) * i2h1;
    v2 dpz = (pzp2 - pzm2) * i2h2;

    v2 irho;
    irho.x = __builtin_amdgcn_rcpf(RR.x + 1e-8f);
    irho.y = __builtin_amdgcn_rcpf(RR.y + 1e-8f);

    v2 Rx = (ucx - upx) * invdt + convx + dpx * irho - lapx * nu0 - g0;
    v2 Ry = (ucy - upy) * invdt + convy + dpy * irho - lapy * nu0 - g1v;
    v2 Rz = (ucz - upz) * invdt + convz + dpz * irho - lapz * nu0 - g2v;
    v2 Rc = dXx + dYy + dZz;

    v2 m2 = Rx * Rx + Ry * Ry + Rz * Rz;
    v2 c2 = Rc * Rc;
    float msum = m2.x + m2.y;
    float csum = c2.x + c2.y;

    // wave(64) reduce in fp32, then block, then one atomic pair
    #pragma unroll
    for (int off = 32; off > 0; off >>= 1) {
        msum += __shfl_down(msum, off);
        csum += __shfl_down(csum, off);
    }

    __shared__ double smom[4], scont[4];
    const int wid = threadIdx.x >> 6;
    const int lane = threadIdx.x & 63;
    if (lane == 0) { smom[wid] = (double)msum; scont[wid] = (double)csum; }
    __syncthreads();
    if (threadIdx.x == 0) {
        const double mm = smom[0] + smom[1] + smom[2] + smom[3];
        const double cc = scont[0] + scont[1] + scont[2] + scont[3];
        double* slot = acc + 2 * (blockIdx.x & (NSLOTS - 1));
        unsafeAtomicAdd(slot, mm);
        unsafeAtomicAdd(slot + 1, cc);
    }
}

__global__ __launch_bounds__(256) void ns_finalize_kernel(const double* __restrict__ acc,
                                                          float* __restrict__ out)
{
    const int tid = threadIdx.x;
    double mom = acc[2 * tid];
    double cont = acc[2 * tid + 1];
    #pragma unroll
    for (int off = 32; off > 0; off >>= 1) {
        mom  += __shfl_down(mom, off);
        cont += __shfl_down(cont, off);
    }
    __shared__ double smom[4], scont[4];
    const int wid = tid >> 6;
    const int lane = tid & 63;
    if (lane == 0) { smom[wid] = mom; scont[wid] = cont; }
    __syncthreads();
    if (tid == 0) {
        const double m = (smom[0] + smom[1] + smom[2] + smom[3]) / (double)GTOT;
        const double c = (scont[0] + scont[1] + scont[2] + scont[3]) / (double)GTOT;
        out[0] = (float)(m + 10.0 * c);
        out[1] = (float)m;
        out[2] = (float)c;
    }
}

extern "C" void kernel_launch(void* const* d_in, const int* in_sizes, int n_in,
                              void* d_out, int out_size, void* d_ws, size_t ws_size,
                              hipStream_t stream)
{
    const float* u     = (const float*)d_in[0];
    const float* uprev = (const float*)d_in[1];
    const float* p     = (const float*)d_in[2];
    const float* rho   = (const float*)d_in[3];
    const float* nu    = (const float*)d_in[4];
    const float* h     = (const float*)d_in[5];
    const float* dt    = (const float*)d_in[6];
    const float* grav  = (const float*)d_in[7];

    double* acc = (double*)d_ws;

    (void)hipMemsetAsync(d_ws, 0, NSLOTS * 2 * sizeof(double), stream);

    ns_loss_kernel<<<NBLK, 256, 0, stream>>>(u, uprev, p, rho, nu, h, dt, grav, acc);
    ns_finalize_kernel<<<1, 256, 0, stream>>>(acc, (float*)d_out);
}